// Round 1
// baseline (160.470 us; speedup 1.0000x reference)
//
#include <hip/hip_runtime.h>

#define B_ 4
#define C_ 64
#define H_ 256
#define W_ 256
#define HW_ (H_*W_)
#define MID_ 12

// ---------------- GAP: g[b*C+c] = mean over H*W ----------------
__global__ __launch_bounds__(256) void gap_kernel(const float* __restrict__ in,
                                                  float* __restrict__ g) {
    int bc = blockIdx.x;  // 0 .. B*C-1
    const float4* p4 = (const float4*)(in + (size_t)bc * HW_);
    float sum = 0.f;
    for (int i = threadIdx.x; i < HW_ / 4; i += 256) {
        float4 v = p4[i];
        sum += (v.x + v.y) + (v.z + v.w);
    }
    __shared__ float red[256];
    red[threadIdx.x] = sum;
    __syncthreads();
    for (int s = 128; s > 0; s >>= 1) {
        if (threadIdx.x < s) red[threadIdx.x] += red[threadIdx.x + s];
        __syncthreads();
    }
    if (threadIdx.x == 0) g[bc] = red[0] * (1.0f / HW_);
}

// ------------- channel branch: SE MLP + FilterNorm -> cf (B,C,9) -------------
__global__ __launch_bounds__(256) void cf_kernel(const float* __restrict__ g,
    const float* __restrict__ cw1, const float* __restrict__ cb1,
    const float* __restrict__ cw2, const float* __restrict__ cb2,
    const float* __restrict__ cstd, float* __restrict__ cf) {
    __shared__ float hsm[B_][MID_];
    int tid = threadIdx.x;
    if (tid < B_ * MID_) {
        int b = tid / MID_, m = tid % MID_;
        float acc = cb1[m];
        for (int c = 0; c < C_; ++c) acc = fmaf(g[b * C_ + c], cw1[m * C_ + c], acc);
        hsm[b][m] = fmaxf(acc, 0.f);
    }
    __syncthreads();
    int b = tid >> 6, c = tid & 63;   // 256 threads == B_*C_ pairs
    float v[9];
    float mean = 0.f;
#pragma unroll
    for (int t = 0; t < 9; ++t) {
        int o = c * 9 + t;
        float acc = cb2[o];
#pragma unroll
        for (int m = 0; m < MID_; ++m) acc = fmaf(hsm[b][m], cw2[o * MID_ + m], acc);
        v[t] = acc;
        mean += acc;
    }
    mean *= (1.f / 9.f);
    float var = 0.f;
#pragma unroll
    for (int t = 0; t < 9; ++t) { float d = v[t] - mean; var += d * d; }
    float inv = 1.f / (sqrtf(var * (1.f / 8.f)) + 1e-10f);
#pragma unroll
    for (int t = 0; t < 9; ++t)
        cf[(b * C_ + c) * 9 + t] = (v[t] - mean) * inv * cstd[c * 9 + t];
}

// ------------- fused: spatial 1x1conv + FilterNorm + DDF apply -------------
// grid: (W/64, H/4, B), block 256 = 64x4. Each thread owns one pixel.
template <bool RELU, bool RESID>
__global__ __launch_bounds__(256) void ddf_main(const float* __restrict__ in,
    const float* __restrict__ sw, const float* __restrict__ sb,
    const float* __restrict__ sstd, const float* __restrict__ cf,
    const float* __restrict__ resid, float* __restrict__ out) {
    const int tx = threadIdx.x & 63, ty = threadIdx.x >> 6;
    const int w = blockIdx.x * 64 + tx;
    const int h = blockIdx.y * 4 + ty;
    const int b = blockIdx.z;
    const float* xb = in + (size_t)b * C_ * HW_;

    // phase 1: per-pixel 9-tap spatial filter (dot over 64 channels)
    float s[9];
#pragma unroll
    for (int t = 0; t < 9; ++t) s[t] = sb[t];
    {
        const float* xp = xb + h * W_ + w;
        for (int c = 0; c < C_; ++c) {
            float xv = xp[(size_t)c * HW_];
#pragma unroll
            for (int t = 0; t < 9; ++t) s[t] = fmaf(xv, sw[t * C_ + c], s[t]);
        }
    }
    // FilterNorm over the 9 taps (unbiased std, ddof=1)
    float mean = 0.f;
#pragma unroll
    for (int t = 0; t < 9; ++t) mean += s[t];
    mean *= (1.f / 9.f);
    float var = 0.f;
#pragma unroll
    for (int t = 0; t < 9; ++t) { float d = s[t] - mean; var += d * d; }
    float inv = 1.f / (sqrtf(var * (1.f / 8.f)) + 1e-10f);
#pragma unroll
    for (int t = 0; t < 9; ++t) s[t] = (s[t] - mean) * inv * sstd[t];

    // phase 2: apply decoupled dynamic filter per channel
    const bool rok0 = (h > 0), rok2 = (h < H_ - 1);
    const bool cok0 = (w > 0), cok2 = (w < W_ - 1);
    const float* cfb = cf + b * (C_ * 9);
    const size_t base = (size_t)h * W_ + w;
    const size_t bbase = (size_t)b * C_ * HW_ + base;
    for (int c = 0; c < C_; ++c) {
        const float* xc = xb + (size_t)c * HW_ + base;
        float acc = 0.f;
#pragma unroll
        for (int i = 0; i < 3; ++i) {
            const bool rok = (i == 0) ? rok0 : ((i == 2) ? rok2 : true);
#pragma unroll
            for (int j = 0; j < 3; ++j) {
                const bool cok = (j == 0) ? cok0 : ((j == 2) ? cok2 : true);
                float xv = (rok && cok) ? xc[(i - 1) * W_ + (j - 1)] : 0.f;
                acc = fmaf(xv, cfb[c * 9 + i * 3 + j] * s[i * 3 + j], acc);
            }
        }
        if (RELU) acc = fmaxf(acc, 0.f);
        size_t oidx = bbase + (size_t)c * HW_;
        if (RESID) acc += resid[oidx];
        out[oidx] = acc;
    }
}

extern "C" void kernel_launch(void* const* d_in, const int* in_sizes, int n_in,
                              void* d_out, int out_size, void* d_ws, size_t ws_size,
                              hipStream_t stream) {
    const float* x     = (const float*)d_in[0];
    const float* sw1   = (const float*)d_in[1];
    const float* sb1   = (const float*)d_in[2];
    const float* sstd1 = (const float*)d_in[3];
    const float* cw1_1 = (const float*)d_in[4];
    const float* cb1_1 = (const float*)d_in[5];
    const float* cw2_1 = (const float*)d_in[6];
    const float* cb2_1 = (const float*)d_in[7];
    const float* cstd1 = (const float*)d_in[8];
    const float* sw2   = (const float*)d_in[9];
    const float* sb2   = (const float*)d_in[10];
    const float* sstd2 = (const float*)d_in[11];
    const float* cw1_2 = (const float*)d_in[12];
    const float* cb1_2 = (const float*)d_in[13];
    const float* cw2_2 = (const float*)d_in[14];
    const float* cb2_2 = (const float*)d_in[15];
    const float* cstd2 = (const float*)d_in[16];

    const size_t n_out1 = (size_t)B_ * C_ * HW_;            // 16,777,216 floats
    const size_t need = (n_out1 + 256 + B_ * C_ * 9) * sizeof(float);
    if (ws_size < need) return;  // workspace too small; fail validation cleanly

    float* out1 = (float*)d_ws;
    float* g    = out1 + n_out1;
    float* cfb  = g + 256;
    float* out  = (float*)d_out;

    dim3 grid(W_ / 64, H_ / 4, B_);

    // pass 1: out1 = relu(ddf(x))
    gap_kernel<<<B_ * C_, 256, 0, stream>>>(x, g);
    cf_kernel<<<1, 256, 0, stream>>>(g, cw1_1, cb1_1, cw2_1, cb2_1, cstd1, cfb);
    ddf_main<true, false><<<grid, 256, 0, stream>>>(x, sw1, sb1, sstd1, cfb, nullptr, out1);

    // pass 2: out = x + ddf(out1)
    gap_kernel<<<B_ * C_, 256, 0, stream>>>(out1, g);
    cf_kernel<<<1, 256, 0, stream>>>(g, cw1_2, cb1_2, cw2_2, cb2_2, cstd2, cfb);
    ddf_main<false, true><<<grid, 256, 0, stream>>>(out1, sw2, sb2, sstd2, cfb, x, out);
}